// Round 9
// baseline (177.149 us; speedup 1.0000x reference)
//
#include <hip/hip_runtime.h>
#include <hip/hip_cooperative_groups.h>
#include <cstdint>
#include <cstddef>

namespace cg = cooperative_groups;

typedef unsigned short u16;
typedef unsigned int u32;
typedef u16 u16x4 __attribute__((ext_vector_type(4)));
typedef u16 u16x8 __attribute__((ext_vector_type(8)));
typedef u32 u32x4 __attribute__((ext_vector_type(4)));
typedef _Float16 f16x2 __attribute__((ext_vector_type(2)));
typedef _Float16 f16x8 __attribute__((ext_vector_type(8)));
typedef float f32x4 __attribute__((ext_vector_type(4)));

#define B_   2
#define N_   2048
#define F_   512
#define D_   512
#define W_   128
#define E3   1536
#define MTOT 4096
#define XELEMS (MTOT * F_)   /* 2,097,152 */
#define WELEMS (E3 * F_)     /* 786,432 */
#define QK_ELEMS (MTOT * D_) /* 2,097,152 */

#define TQA 16
#define SA 200
#define SP 208

__device__ __forceinline__ u16 f2h(float f) {
  return __builtin_bit_cast(u16, (_Float16)f);
}
__device__ __forceinline__ u32 pk2h(float a, float b) {
  return __builtin_bit_cast(u32, __builtin_amdgcn_cvt_pkrtz(a, b));
}
__device__ __forceinline__ f32x4 mfma_f16(u16x8 a, u16x8 b, f32x4 c) {
  return __builtin_amdgcn_mfma_f32_16x16x32_f16(
      __builtin_bit_cast(f16x8, a), __builtin_bit_cast(f16x8, b), c, 0, 0, 0);
}
__device__ __forceinline__ void glds16(const u16* g, u16* l) {
  __builtin_amdgcn_global_load_lds(
      (const __attribute__((address_space(1))) void*)g,
      (__attribute__((address_space(3))) void*)l, 16, 0, 0);
}

/* One cooperative kernel: cvt -> sync -> QKV GEMM -> sync -> attention.
 * 256 blocks x 512 threads (1 block/CU co-resident). One 33 KB LDS pool
 * aliased by all three phases. */
__global__ __launch_bounds__(512, 2) void mega(const float* __restrict__ X,
                                               const float* __restrict__ Wl,
                                               u16* __restrict__ Xf, u16* __restrict__ Wf,
                                               u16* __restrict__ Qf, u16* __restrict__ Kf,
                                               u16* __restrict__ Vt,
                                               float* __restrict__ Out) {
  __shared__ __align__(16) u32 shraw[8320]; /* 33280 B, aliased per phase */
  u16* sm16 = (u16*)shraw;

  cg::grid_group grid = cg::this_grid();

  const int t = threadIdx.x;
  const int lane = t & 63;
  const int wave = t >> 6; /* 0..7 */
  const int qd = lane >> 4;
  const int l16 = lane & 15;

  /* ================= Phase 0: fp32 -> fp16 planes ================= */
  {
    const int n4X = XELEMS / 4;
    const int n4T = (XELEMS + WELEMS) / 4; /* 720896 */
    for (int i = blockIdx.x * 512 + t; i < n4T; i += 256 * 512) {
      u16x4 h;
      if (i < n4X) {
        float4 v = ((const float4*)X)[i];
        h.x = f2h(v.x); h.y = f2h(v.y); h.z = f2h(v.z); h.w = f2h(v.w);
        ((u16x4*)Xf)[i] = h;
      } else {
        int j = i - n4X;
        float4 v = ((const float4*)Wl)[j];
        h.x = f2h(v.x); h.y = f2h(v.y); h.z = f2h(v.z); h.w = f2h(v.w);
        ((u16x4*)Wf)[j] = h;
      }
    }
  }
  grid.sync();

  /* ================= Phase 1: QKV GEMM =================
   * 192 active blocks; tile 256(M) x 128(E); 8 waves of 64x64.
   * glds 16B staging + XOR chunk swizzle; 16 MFMA : 8 ds_read_b128 :
   * 3 glds per wave per K-iter. */
  if (blockIdx.x < 192) {
    u16* sA = sm16;        /* [256][32] u16 */
    u16* sB = sm16 + 8192; /* [128][32] u16 */

    const int my = blockIdx.x / 12;
    const int ey = blockIdx.x % 12;
    const int m0 = my * 256;
    const int e0 = ey * 128;
    const int wm = (wave >> 1) * 64;
    const int we = (wave & 1) * 64;

    const int lrow = lane >> 2;
    const int cg_ = (lane & 3) ^ ((lrow >> 1) & 3);
    const int lkc = cg_ * 8;

    f32x4 acc[4][4];
#pragma unroll
    for (int i = 0; i < 4; ++i)
#pragma unroll
      for (int j = 0; j < 4; ++j) acc[i][j] = (f32x4){0.f, 0.f, 0.f, 0.f};

    /* 24 staging issues (A:16, B:8); wave w does issues 3w..3w+2 */
    const u16* gsrc[3];
    u16* ldst[3];
#pragma unroll
    for (int s = 0; s < 3; ++s) {
      int ib = wave * 3 + s;
      if (ib < 16) {
        int row0 = ib * 16;
        gsrc[s] = Xf + (size_t)(m0 + row0 + lrow) * F_ + lkc;
        ldst[s] = sA + row0 * 32;
      } else {
        int row0 = (ib - 16) * 16;
        gsrc[s] = Wf + (size_t)(e0 + row0 + lrow) * F_ + lkc;
        ldst[s] = sB + row0 * 32;
      }
    }

    const int swz = (l16 >> 1) & 3;
    const int rdoff = (qd ^ swz) * 8;

    for (int k0 = 0; k0 < F_; k0 += 32) {
#pragma unroll
      for (int s = 0; s < 3; ++s) glds16(gsrc[s] + k0, ldst[s]);
      __syncthreads();

      u16x8 fA[4], fB[4];
#pragma unroll
      for (int mi = 0; mi < 4; ++mi)
        fA[mi] = *(const u16x8*)&sA[(wm + mi * 16 + l16) * 32 + rdoff];
#pragma unroll
      for (int ei = 0; ei < 4; ++ei)
        fB[ei] = *(const u16x8*)&sB[(we + ei * 16 + l16) * 32 + rdoff];
#pragma unroll
      for (int mi = 0; mi < 4; ++mi)
#pragma unroll
        for (int ei = 0; ei < 4; ++ei)
          acc[mi][ei] = mfma_f16(fA[mi], fB[ei], acc[mi][ei]);
      __syncthreads();
    }

    /* Epilogue. C/D layout: row = qd*4 + reg, col = lane&15. */
    const int third = e0 >> 9; /* 0=Q 1=K 2=V */
    if (third < 2) {
      /* Q/K: shfl-pair + cvt_pkrtz -> u32 stores (cols 2k,2k+1).
       * Even l16 stores rows +0,+1; odd l16 rows +2,+3. */
      u16* P = third ? Kf : Qf;
      const int ecol0 = (e0 & 511) + we;
      const int odd = l16 & 1;
#pragma unroll
      for (int mi = 0; mi < 4; ++mi)
#pragma unroll
        for (int ei = 0; ei < 4; ++ei) {
          float x0 = acc[mi][ei][0], x1 = acc[mi][ei][1];
          float x2 = acc[mi][ei][2], x3 = acc[mi][ei][3];
          float t0 = __shfl_xor(x0, 1), t1 = __shfl_xor(x1, 1);
          float t2 = __shfl_xor(x2, 1), t3 = __shfl_xor(x3, 1);
          u32 pa = odd ? pk2h(t2, x2) : pk2h(x0, t0);
          u32 pb = odd ? pk2h(t3, x3) : pk2h(x1, t1);
          int mrow = m0 + wm + mi * 16 + qd * 4 + odd * 2;
          int colp = ecol0 + ei * 16 + (l16 & ~1);
          *(u32*)(P + (size_t)mrow * D_ + colp) = pa;
          *(u32*)(P + (size_t)(mrow + 1) * D_ + colp) = pb;
        }
    } else {
      /* V: wave-private LDS transpose in 16-e-row chunks -> coalesced
       * Vt[b][d][n] stores. vbuf aliases staging (K-loop's trailing
       * __syncthreads fenced it). NOTE the m-address includes the wave's
       * M-strip offset `wm` (R8 bug: omitted -> all waves overwrote the
       * tile base and m 64..255 kept 0xAA poison). */
      u16* vbuf = sm16 + wave * 1056; /* [16][66] u16 */
      const int dbase = (e0 - 1024) + we;
      const int mb = (m0 & 2047) + wm;
      const int bb = m0 >> 11;
      u16* vt = Vt + (size_t)bb * (D_ * N_);
#pragma unroll
      for (int ei = 0; ei < 4; ++ei) {
#pragma unroll
        for (int mi = 0; mi < 4; ++mi)
#pragma unroll
          for (int r2 = 0; r2 < 2; ++r2) {
            int m_in = mi * 16 + qd * 4 + r2 * 2;
            u32 p = pk2h(acc[mi][ei][r2 * 2], acc[mi][ei][r2 * 2 + 1]);
            *(u32*)&vbuf[l16 * 66 + m_in] = p;
          }
        __builtin_amdgcn_s_waitcnt(0); /* wave-private: drain lgkm */
        int er = lane >> 2;
        int mc = lane & 3;
        u32 q0[8];
#pragma unroll
        for (int c4 = 0; c4 < 8; ++c4)
          q0[c4] = *(const u32*)&vbuf[er * 66 + mc * 16 + c4 * 2];
        u16* gp = vt + (size_t)(dbase + ei * 16 + er) * N_ + mb + mc * 16;
        *(u32x4*)gp = (u32x4){q0[0], q0[1], q0[2], q0[3]};
        *(u32x4*)(gp + 8) = (u32x4){q0[4], q0[5], q0[6], q0[7]};
        __builtin_amdgcn_s_waitcnt(0); /* reads done before next chunk */
      }
    }
  }
  grid.sync();

  /* ================= Phase 2: sliding-window attention =================
   * Block = 16 queries; phase1 split-K across wave pairs; zero-pad rows
   * (r<0) get logit 0.0 in the denominator, P forced 0. */
  {
    float* attp = (float*)shraw;      /* [2][TQA][SA] f32 = 25.6 KB */
    u16* pSp = sm16 + 12800;          /* [TQA][SP] u16 = 6.7 KB */

    const int m0 = blockIdx.x * TQA;
    const int b = m0 >> 11;
    const int n0 = m0 & 2047;
    const int jw = wave & 3;
    const int kh = wave >> 2;

    f32x4 acc[3];
#pragma unroll
    for (int nt = 0; nt < 3; ++nt) acc[nt] = (f32x4){0.f, 0.f, 0.f, 0.f};

    const size_t qrow = (size_t)(m0 + l16) * D_ + qd * 8;
    for (int ks = kh * 8; ks < kh * 8 + 8; ++ks) {
      u16x8 qv = *(const u16x8*)(Qf + qrow + ks * 32);
#pragma unroll
      for (int nt = 0; nt < 3; ++nt) {
        int j = (jw * 3 + nt) * 16 + l16;
        int rl = n0 - 128 + j;
        int rg = b * N_ + (rl > 0 ? rl : 0);
        u16x8 kv = *(const u16x8*)(Kf + (size_t)rg * D_ + ks * 32 + qd * 8);
        acc[nt] = mfma_f16(qv, kv, acc[nt]);
      }
    }
#pragma unroll
    for (int nt = 0; nt < 3; ++nt)
#pragma unroll
      for (int r = 0; r < 4; ++r)
        attp[kh * (TQA * SA) + (qd * 4 + r) * SA + (jw * 3 + nt) * 16 + l16] =
            acc[nt][r];
    __syncthreads();

    {
      const int i = t >> 5;
      const int c = t & 31;
      float ev[6];
      float mx = -1e30f;
#pragma unroll
      for (int s = 0; s < 6; ++s) {
        int j = c * 6 + s;
        bool inw = (j >= i + 1) && (j <= i + 128);
        float v = -1e30f;
        if (inw)
          v = (n0 - 128 + j < 0)
                  ? 0.f
                  : attp[i * SA + j] + attp[TQA * SA + i * SA + j];
        ev[s] = v;
        mx = fmaxf(mx, v);
      }
      mx = fmaxf(mx, __shfl_xor(mx, 1));
      mx = fmaxf(mx, __shfl_xor(mx, 2));
      mx = fmaxf(mx, __shfl_xor(mx, 4));
      mx = fmaxf(mx, __shfl_xor(mx, 8));
      mx = fmaxf(mx, __shfl_xor(mx, 16));
      float sum = 0.f;
#pragma unroll
      for (int s = 0; s < 6; ++s) {
        ev[s] = (ev[s] > -1e29f) ? __expf(ev[s] - mx) : 0.f;
        sum += ev[s];
      }
      sum += __shfl_xor(sum, 1);
      sum += __shfl_xor(sum, 2);
      sum += __shfl_xor(sum, 4);
      sum += __shfl_xor(sum, 8);
      sum += __shfl_xor(sum, 16);
      const float inv = 1.f / sum;
#pragma unroll
      for (int s = 0; s < 6; ++s) {
        int j = c * 6 + s;
        bool zv = (n0 - 128 + j) < 0;
        pSp[i * SP + j] = zv ? (u16)0 : f2h(ev[s] * inv);
      }
    }
    __syncthreads();

    f32x4 oacc[4];
#pragma unroll
    for (int nt = 0; nt < 4; ++nt) oacc[nt] = (f32x4){0.f, 0.f, 0.f, 0.f};

    const u16* vtb = Vt + (size_t)b * (D_ * N_);
    for (int kk = 0; kk < 6; ++kk) {
      u16x8 pa = *(const u16x8*)&pSp[l16 * SP + kk * 32 + qd * 8];
      const int rl = n0 - 128 + kk * 32 + qd * 8; /* may be <0: P=0 guards */
#pragma unroll
      for (int nt = 0; nt < 4; ++nt) {
        int d = wave * 64 + nt * 16 + l16;
        u16x8 vv = *(const u16x8*)(vtb + (size_t)d * N_ + rl);
        oacc[nt] = mfma_f16(pa, vv, oacc[nt]);
      }
    }
#pragma unroll
    for (int nt = 0; nt < 4; ++nt)
#pragma unroll
      for (int r = 0; r < 4; ++r)
        Out[(size_t)(m0 + qd * 4 + r) * D_ + wave * 64 + nt * 16 + l16] =
            oacc[nt][r];
  }
}

extern "C" void kernel_launch(void* const* d_in, const int* in_sizes, int n_in,
                              void* d_out, int out_size, void* d_ws, size_t ws_size,
                              hipStream_t stream) {
  const float* x = (const float*)d_in[0];
  const float* wl = (const float*)d_in[1];
  float* out = (float*)d_out;

  u16* Xf = (u16*)d_ws;
  u16* Wf = Xf + XELEMS;
  u16* Qf = Wf + WELEMS;
  u16* Kf = Qf + QK_ELEMS;
  u16* Vt = Kf + QK_ELEMS;

  void* kargs[] = {(void*)&x, (void*)&wl, (void*)&Xf, (void*)&Wf,
                   (void*)&Qf, (void*)&Kf, (void*)&Vt, (void*)&out};
  hipLaunchCooperativeKernel((void*)mega, dim3(256), dim3(512), kargs, 0, stream);
}

// Round 10
// 96.059 us; speedup vs baseline: 1.8442x; 1.8442x over previous
//
#include <hip/hip_runtime.h>
#include <cstdint>
#include <cstddef>

typedef unsigned short u16;
typedef unsigned int u32;
typedef u16 u16x4 __attribute__((ext_vector_type(4)));
typedef u16 u16x8 __attribute__((ext_vector_type(8)));
typedef u32 u32x2 __attribute__((ext_vector_type(2)));
typedef u32 u32x4 __attribute__((ext_vector_type(4)));
typedef _Float16 f16x8 __attribute__((ext_vector_type(8)));
typedef float f32x4 __attribute__((ext_vector_type(4)));

#define B_   2
#define N_   2048
#define F_   512
#define D_   512
#define W_   128
#define E3   1536
#define MTOT 4096
#define XELEMS (MTOT * F_)   /* 2,097,152 */
#define WELEMS (E3 * F_)     /* 786,432 */
#define QK_ELEMS (MTOT * D_) /* 2,097,152 */

__device__ __forceinline__ u16 f2h(float f) {
  return __builtin_bit_cast(u16, (_Float16)f); /* v_cvt_f16_f32, RNE */
}
__device__ __forceinline__ u32 pk2h(float a, float b) {
  return __builtin_bit_cast(u32, __builtin_amdgcn_cvt_pkrtz(a, b));
}
__device__ __forceinline__ f32x4 mfma_f16(u16x8 a, u16x8 b, f32x4 c) {
  return __builtin_amdgcn_mfma_f32_16x16x32_f16(
      __builtin_bit_cast(f16x8, a), __builtin_bit_cast(f16x8, b), c, 0, 0, 0);
}
__device__ __forceinline__ void glds16(const u16* g, u16* l) {
  __builtin_amdgcn_global_load_lds(
      (const __attribute__((address_space(1))) void*)g,
      (__attribute__((address_space(3))) void*)l, 16, 0, 0);
}

/* ---------------- Prepass: fp32 -> fp16 planes for X and W ----------------- */
__global__ __launch_bounds__(256) void cvt_f16(const float* __restrict__ X,
                                               const float* __restrict__ Wl,
                                               u16* __restrict__ Xf, u16* __restrict__ Wf) {
  const int i = blockIdx.x * 256 + threadIdx.x; /* one float4 per thread */
  const int n4X = XELEMS / 4;
  if (i < n4X) {
    float4 v = ((const float4*)X)[i];
    ((u32x2*)Xf)[i] = (u32x2){pk2h(v.x, v.y), pk2h(v.z, v.w)};
  } else {
    int j = i - n4X;
    float4 v = ((const float4*)Wl)[j];
    ((u32x2*)Wf)[j] = (u32x2){pk2h(v.x, v.y), pk2h(v.z, v.w)};
  }
}

/* ---------------- QKV GEMM, fp16 single-pass (m97 structure) ---------------
 * [REVERTED to the 96.56 us R6 structure after the cooperative mega-kernel
 * regressed to 177 us: losing oversubscription + grid.sync fences dwarf the
 * launch gaps they removed.]
 * 128x128 tile, BK=32, 256 thr / 4 waves of 64x64, glds 16B staging, XOR
 * chunk swizzle. Epilogue: Q/K packed u32 stores (shfl-pair + cvt_pkrtz,
 * correctness-proven in R9); V -> fp16 transposed [b][d][n] via LDS. */
#define TM 128
#define TE 128
#define BK 32

__global__ __launch_bounds__(256) void qkv_gemm(const u16* __restrict__ Xf,
                                                const u16* __restrict__ Wf,
                                                u16* __restrict__ Qf,
                                                u16* __restrict__ Kf,
                                                u16* __restrict__ Vt) {
  __shared__ __align__(16) u16 smem[16896]; /* staging 16 KB; vbuf 4x8448 B */
  u16* sA = smem;
  u16* sB = smem + 4096; /* each [128][32] u16, rows 64 B, chunk-swizzled */

  const int tid = threadIdx.x;
  const int m0 = blockIdx.x * TM;
  const int e0 = blockIdx.y * TE;
  const int lane = tid & 63;
  const int wave = tid >> 6;
  const int wm = (wave >> 1) * 64;
  const int we = (wave & 1) * 64;
  const int qd = lane >> 4;
  const int l16 = lane & 15;

  const int lrow = lane >> 2;
  const int cg = (lane & 3) ^ ((lrow >> 1) & 3);
  const int lkc = cg * 8;

  f32x4 acc[4][4];
#pragma unroll
  for (int i = 0; i < 4; ++i)
#pragma unroll
    for (int j = 0; j < 4; ++j) acc[i][j] = (f32x4){0.f, 0.f, 0.f, 0.f};

  const int r0 = wave * 32;
  const size_t ga0 = (size_t)(m0 + r0 + lrow) * F_ + lkc;
  const size_t ga1 = (size_t)(m0 + r0 + 16 + lrow) * F_ + lkc;
  const size_t gb0 = (size_t)(e0 + r0 + lrow) * F_ + lkc;
  const size_t gb1 = (size_t)(e0 + r0 + 16 + lrow) * F_ + lkc;
  u16* lA0 = sA + r0 * 32;
  u16* lA1 = sA + (r0 + 16) * 32;
  u16* lB0 = sB + r0 * 32;
  u16* lB1 = sB + (r0 + 16) * 32;

  const int swz = (l16 >> 1) & 3;
  const int rdoff = (qd ^ swz) * 8;

  for (int k0 = 0; k0 < F_; k0 += BK) {
    glds16(Xf + ga0 + k0, lA0);
    glds16(Xf + ga1 + k0, lA1);
    glds16(Wf + gb0 + k0, lB0);
    glds16(Wf + gb1 + k0, lB1);
    __syncthreads();

    u16x8 fA[4], fB[4];
#pragma unroll
    for (int mi = 0; mi < 4; ++mi)
      fA[mi] = *(const u16x8*)&sA[(wm + mi * 16 + l16) * 32 + rdoff];
#pragma unroll
    for (int ei = 0; ei < 4; ++ei)
      fB[ei] = *(const u16x8*)&sB[(we + ei * 16 + l16) * 32 + rdoff];
#pragma unroll
    for (int mi = 0; mi < 4; ++mi)
#pragma unroll
      for (int ei = 0; ei < 4; ++ei)
        acc[mi][ei] = mfma_f16(fA[mi], fB[ei], acc[mi][ei]);
    __syncthreads();
  }

  /* C/D layout: row = qd*4 + reg, col = lane&15 */
  const int third = e0 >> 9; /* 0=Q, 1=K, 2=V */
  if (third < 2) {
    /* Q/K: shfl-pair + cvt_pkrtz -> u32 stores (cols 2k,2k+1).
     * Even l16 stores rows +0,+1; odd l16 rows +2,+3. Proven in R9. */
    u16* P = third ? Kf : Qf;
    const int ecol0 = (e0 & 511) + we;
    const int odd = l16 & 1;
#pragma unroll
    for (int mi = 0; mi < 4; ++mi)
#pragma unroll
      for (int ei = 0; ei < 4; ++ei) {
        float x0 = acc[mi][ei][0], x1 = acc[mi][ei][1];
        float x2 = acc[mi][ei][2], x3 = acc[mi][ei][3];
        float t0 = __shfl_xor(x0, 1), t1 = __shfl_xor(x1, 1);
        float t2 = __shfl_xor(x2, 1), t3 = __shfl_xor(x3, 1);
        u32 pa = odd ? pk2h(t2, x2) : pk2h(x0, t0);
        u32 pb = odd ? pk2h(t3, x3) : pk2h(x1, t1);
        int mrow = m0 + wm + mi * 16 + qd * 4 + odd * 2;
        int colp = ecol0 + ei * 16 + (l16 & ~1);
        *(u32*)(P + (size_t)mrow * D_ + colp) = pa;
        *(u32*)(P + (size_t)(mrow + 1) * D_ + colp) = pb;
      }
  } else {
    /* V: per-wave 64x64 LDS transpose (stride 66 u16), coalesced Vt write.
     * m-address includes the wave's M-strip offset wm. */
    u16* vbuf = smem + wave * 4224; /* [64][66] u16 */
#pragma unroll
    for (int mi = 0; mi < 4; ++mi)
#pragma unroll
      for (int ei = 0; ei < 4; ++ei)
#pragma unroll
        for (int r2 = 0; r2 < 2; ++r2) {
          int e_in = ei * 16 + l16;
          int m_in = mi * 16 + qd * 4 + r2 * 2;
          u32 p = pk2h(acc[mi][ei][r2 * 2], acc[mi][ei][r2 * 2 + 1]);
          *(u32*)&vbuf[e_in * 66 + m_in] = p;
        }
    __builtin_amdgcn_s_waitcnt(0); /* drain lgkm before wave-local readback */
    const int dbase = (e0 - 1024) + we;
    const int mb = (m0 & 2047) + wm;
    const int bb = m0 >> 11;
    u16* vt = Vt + (size_t)bb * (D_ * N_);
#pragma unroll
    for (int it = 0; it < 4; ++it) {
      int e_in = it * 16 + (lane >> 2);
      int mc = lane & 3;
      u32 q0[8];
#pragma unroll
      for (int c4 = 0; c4 < 8; ++c4)
        q0[c4] = *(const u32*)&vbuf[e_in * 66 + mc * 16 + c4 * 2];
      u16* gp = vt + (size_t)(dbase + e_in) * N_ + mb + mc * 16;
      *(u32x4*)gp = (u32x4){q0[0], q0[1], q0[2], q0[3]};
      *(u32x4*)(gp + 8) = (u32x4){q0[4], q0[5], q0[6], q0[7]};
    }
  }
}

/* ---------------- MFMA sliding-window attention (R6-proven) ----------------
 * 512 threads, 8 waves, TQA=16. Phase 1 split-K; phase 3 wave owns 64 d-cols.
 * Zero-pad rows (r<0): logit 0.0 in the softmax denominator, P forced 0. */
#define TQA 16
#define SA 200
#define SP 208

__global__ __launch_bounds__(512) void attn_kernel(const u16* __restrict__ Qf,
                                                   const u16* __restrict__ Kf,
                                                   const u16* __restrict__ Vt,
                                                   float* __restrict__ Out) {
  const int m0 = blockIdx.x * TQA;
  const int b = m0 >> 11;
  const int n0 = m0 & 2047;
  const int t = threadIdx.x;
  const int lane = t & 63;
  const int w = t >> 6;
  const int qd = lane >> 4;
  const int l16 = lane & 15;

  __shared__ __align__(16) float att[2][TQA][SA];
  __shared__ __align__(16) u16 pS[TQA][SP];

  const int jw = w & 3;
  const int kh = w >> 2;

  /* Phase 1: logits = Q K^T, split-K across wave pairs. */
  f32x4 acc[3];
#pragma unroll
  for (int nt = 0; nt < 3; ++nt) acc[nt] = (f32x4){0.f, 0.f, 0.f, 0.f};

  const size_t qrow = (size_t)(m0 + l16) * D_ + qd * 8;
  for (int ks = kh * 8; ks < kh * 8 + 8; ++ks) {
    u16x8 qv = *(const u16x8*)(Qf + qrow + ks * 32);
#pragma unroll
    for (int nt = 0; nt < 3; ++nt) {
      int j = (jw * 3 + nt) * 16 + l16;
      int rl = n0 - 128 + j;
      int rg = b * N_ + (rl > 0 ? rl : 0);
      u16x8 kv = *(const u16x8*)(Kf + (size_t)rg * D_ + ks * 32 + qd * 8);
      acc[nt] = mfma_f16(qv, kv, acc[nt]);
    }
  }
#pragma unroll
  for (int nt = 0; nt < 3; ++nt)
#pragma unroll
    for (int r = 0; r < 4; ++r)
      att[kh][qd * 4 + r][(jw * 3 + nt) * 16 + l16] = acc[nt][r];
  __syncthreads();

  /* Phase 2: softmax per query i over j in [i+1, i+128]; 32 thr/row. */
  {
    const int i = t >> 5;
    const int c = t & 31;
    float ev[6];
    float mx = -1e30f;
#pragma unroll
    for (int s = 0; s < 6; ++s) {
      int j = c * 6 + s;
      bool inw = (j >= i + 1) && (j <= i + 128);
      float v = -1e30f;
      if (inw) v = (n0 - 128 + j < 0) ? 0.f : att[0][i][j] + att[1][i][j];
      ev[s] = v;
      mx = fmaxf(mx, v);
    }
    mx = fmaxf(mx, __shfl_xor(mx, 1));
    mx = fmaxf(mx, __shfl_xor(mx, 2));
    mx = fmaxf(mx, __shfl_xor(mx, 4));
    mx = fmaxf(mx, __shfl_xor(mx, 8));
    mx = fmaxf(mx, __shfl_xor(mx, 16));
    float sum = 0.f;
#pragma unroll
    for (int s = 0; s < 6; ++s) {
      ev[s] = (ev[s] > -1e29f) ? __expf(ev[s] - mx) : 0.f;
      sum += ev[s];
    }
    sum += __shfl_xor(sum, 1);
    sum += __shfl_xor(sum, 2);
    sum += __shfl_xor(sum, 4);
    sum += __shfl_xor(sum, 8);
    sum += __shfl_xor(sum, 16);
    const float inv = 1.f / sum;
#pragma unroll
    for (int s = 0; s < 6; ++s) {
      int j = c * 6 + s;
      bool zv = (n0 - 128 + j) < 0;
      pS[i][j] = zv ? (u16)0 : f2h(ev[s] * inv);
    }
  }
  __syncthreads();

  /* Phase 3: Out = P V; wave w owns d-cols [w*64, w*64+64). */
  f32x4 oacc[4];
#pragma unroll
  for (int nt = 0; nt < 4; ++nt) oacc[nt] = (f32x4){0.f, 0.f, 0.f, 0.f};

  const u16* vtb = Vt + (size_t)b * (D_ * N_);
  for (int kk = 0; kk < 6; ++kk) {
    u16x8 pa = *(const u16x8*)&pS[l16][kk * 32 + qd * 8];
    const int rl = n0 - 128 + kk * 32 + qd * 8; /* may be <0: P=0 guards */
#pragma unroll
    for (int nt = 0; nt < 4; ++nt) {
      int d = w * 64 + nt * 16 + l16;
      u16x8 vv = *(const u16x8*)(vtb + (size_t)d * N_ + rl);
      oacc[nt] = mfma_f16(pa, vv, oacc[nt]);
    }
  }
#pragma unroll
  for (int nt = 0; nt < 4; ++nt)
#pragma unroll
    for (int r = 0; r < 4; ++r)
      Out[(size_t)(m0 + qd * 4 + r) * D_ + w * 64 + nt * 16 + l16] = oacc[nt][r];
}

extern "C" void kernel_launch(void* const* d_in, const int* in_sizes, int n_in,
                              void* d_out, int out_size, void* d_ws, size_t ws_size,
                              hipStream_t stream) {
  const float* x = (const float*)d_in[0];
  const float* wl = (const float*)d_in[1];
  float* out = (float*)d_out;

  u16* Xf = (u16*)d_ws;
  u16* Wf = Xf + XELEMS;
  u16* Qf = Wf + WELEMS;
  u16* Kf = Qf + QK_ELEMS;
  u16* Vt = Kf + QK_ELEMS;

  cvt_f16<<<(XELEMS + WELEMS) / 4 / 256, 256, 0, stream>>>(x, wl, Xf, Wf);
  dim3 g1(MTOT / TM, E3 / TE); /* 32 x 12 */
  qkv_gemm<<<g1, 256, 0, stream>>>(Xf, Wf, Qf, Kf, Vt);
  attn_kernel<<<MTOT / TQA, 512, 0, stream>>>(Qf, Kf, Vt, out);
}